// Round 4
// baseline (348.574 us; speedup 1.0000x reference)
//
#include <hip/hip_runtime.h>
#include <hip/hip_cooperative_groups.h>
#include <math.h>

namespace cg = cooperative_groups;

#define B 4
#define N 256
#define DIN 4
#define D 64
#define NH 4
#define NL 2
#define DH 16

constexpr float EPS = 1e-5f;
constexpr float SLOPE = 0.01f;

struct Params {
    const float* feature;
    const float* W1; const float* b1;
    const float* mw; const float* mb;
    const float* bn_g; const float* bn_b;
    const float* Wq; const float* bq;
    const float* Wk; const float* bk;
    const float* Wv; const float* bv;
    const float* Wo; const float* bo;
    const float* ln1g; const float* ln1b;
    const float* Wff1; const float* bff1;
    const float* Wff2; const float* bff2;
    const float* ln2g; const float* ln2b;
    float* rs; float* h; float* mean; float* inv;
    float* q; float* k; float* v;
    float* x;
};

// ---------------------------------------------------------------------------
// One cooperative kernel, 256 blocks x 256 threads (1 block/CU), 6 grid syncs.
// Phases:
//  P1 rowsum      : wave = (b,i) row, lane owns 4 j's; wave-shuffle reduce.
//  P2 aggregate   : block = (b, 4-j tile); thread = i reads 64B contiguous.
//  P3 bn stats    : blocks 0..63, one channel each.
//  per layer l:
//  P4 qkv         : 4 tokens/block; l==0 folds BN-apply into x materialization.
//  P5 layer tail  : attention (K/V in regs) + oproj + LN1 + FFN + LN2.
// ---------------------------------------------------------------------------
__global__ void __launch_bounds__(256) k_all(Params P) {
    cg::grid_group grid = cg::this_grid();
    __shared__ float sm[1024];
    float* M = sm;       // [4][4]  alive P1-P2
    float* C = sm + 16;  // [4]
    int t = threadIdx.x;
    int lane = t & 63, w = t >> 6;
    int cb = blockIdx.x;

    // ---- precompute M = W1·mw^T (4x4), C = b1·mw + mb ----
    if (t < 16) {
        int n = t >> 2, kk = t & 3;
        float s = 0.f;
        for (int d = 0; d < D; ++d) s += P.W1[kk * D + d] * P.mw[n * D + d];
        M[t] = s;
    } else if (t < 20) {
        int n = t - 16;
        float s = P.mb[n];
        for (int d = 0; d < D; ++d) s += P.b1[d] * P.mw[n * D + d];
        C[n] = s;
    }
    __syncthreads();

    // ---- P1: rowsum. wave w -> row bi = cb*4+w, lane owns j = lane+64m ----
    {
        int bi = cb * 4 + w;
        const float4* fb = (const float4*)(P.feature) + (size_t)bi * N;
        float sn[4] = {0.f, 0.f, 0.f, 0.f};
#pragma unroll
        for (int m = 0; m < 4; ++m) {
            float4 f = fb[lane + 64 * m];
#pragma unroll
            for (int n = 0; n < 4; ++n) {
                float s = C[n] + f.x * M[n*4+0] + f.y * M[n*4+1] + f.z * M[n*4+2] + f.w * M[n*4+3];
                s = (s >= 0.f) ? s : SLOPE * s;
                sn[n] += __expf(s);
            }
        }
#pragma unroll
        for (int n = 0; n < 4; ++n)
#pragma unroll
            for (int off = 32; off > 0; off >>= 1) sn[n] += __shfl_xor(sn[n], off);
        if (lane == 0) {
            float4 o = {sn[0], sn[1], sn[2], sn[3]};
            *(float4*)(P.rs + (size_t)bi * 4) = o;
        }
    }
    grid.sync();

    // ---- P2: aggregate. block -> (b, j0..j0+3); thread = i (64B contiguous) ----
    {
        int b = cb >> 6, j0 = (cb & 63) * 4;
        int i = t;
        const float4* fb = (const float4*)(P.feature) + ((size_t)(b * N + i) * N + j0);
        float4 f[4];
#pragma unroll
        for (int jj = 0; jj < 4; ++jj) f[jj] = fb[jj];
        float4 r4 = *(const float4*)(P.rs + (size_t)(b * N + i) * 4);
        float rinv[4] = {1.f / r4.x, 1.f / r4.y, 1.f / r4.z, 1.f / r4.w};
        float acc[4][5];
#pragma unroll
        for (int jj = 0; jj < 4; ++jj) {
            float wbar = 0.f;
#pragma unroll
            for (int n = 0; n < 4; ++n) {
                float s = C[n] + f[jj].x * M[n*4+0] + f[jj].y * M[n*4+1] + f[jj].z * M[n*4+2] + f[jj].w * M[n*4+3];
                s = (s >= 0.f) ? s : SLOPE * s;
                wbar += __expf(s) * rinv[n];
            }
            wbar *= 0.25f;
            acc[jj][0] = wbar * f[jj].x; acc[jj][1] = wbar * f[jj].y;
            acc[jj][2] = wbar * f[jj].z; acc[jj][3] = wbar * f[jj].w;
            acc[jj][4] = wbar;
        }
#pragma unroll
        for (int jj = 0; jj < 4; ++jj)
#pragma unroll
            for (int c = 0; c < 5; ++c)
#pragma unroll
                for (int off = 32; off > 0; off >>= 1) acc[jj][c] += __shfl_xor(acc[jj][c], off);
        float* part = sm + 32;   // [4 waves][20]
        if (lane == 0) {
#pragma unroll
            for (int jj = 0; jj < 4; ++jj)
#pragma unroll
                for (int c = 0; c < 5; ++c) part[w * 20 + jj * 5 + c] = acc[jj][c];
        }
        __syncthreads();
        float* gacc = sm + 112;  // [4][5]
        if (t < 20) gacc[t] = part[t] + part[20 + t] + part[40 + t] + part[60 + t];
        __syncthreads();
        // h write: wave w = jj, lane = channel
        float hv = gacc[w * 5 + 4] * P.b1[lane];
#pragma unroll
        for (int kk = 0; kk < 4; ++kk) hv += gacc[w * 5 + kk] * P.W1[kk * D + lane];
        P.h[((size_t)(b * N + j0 + w)) * D + lane] = hv;
    }
    grid.sync();

    // ---- P3: BN stats. blocks 0..63, channel = cb ----
    if (cb < D) {
        int d = cb;
        float s = 0.f, sq = 0.f;
        for (int r = t; r < B * N; r += 256) {
            float v0 = P.h[(size_t)r * D + d];
            s += v0; sq += v0 * v0;
        }
#pragma unroll
        for (int off = 32; off > 0; off >>= 1) {
            s += __shfl_xor(s, off);
            sq += __shfl_xor(sq, off);
        }
        if (lane == 0) { sm[w] = s; sm[4 + w] = sq; }
        __syncthreads();
        if (t == 0) {
            float S = sm[0] + sm[1] + sm[2] + sm[3];
            float Q = sm[4] + sm[5] + sm[6] + sm[7];
            float m0 = S * (1.0f / (B * N));
            float var = Q * (1.0f / (B * N)) - m0 * m0;
            P.mean[d] = m0;
            P.inv[d] = rsqrtf(var + EPS);
        }
    }
    grid.sync();

    for (int l = 0; l < NL; ++l) {
        const float* Wq = P.Wq + (size_t)l * D * D, *bq = P.bq + (size_t)l * D;
        const float* Wk = P.Wk + (size_t)l * D * D, *bk = P.bk + (size_t)l * D;
        const float* Wv = P.Wv + (size_t)l * D * D, *bv = P.bv + (size_t)l * D;
        const float* Wo = P.Wo + (size_t)l * D * D, *bo = P.bo + (size_t)l * D;
        const float* ln1g = P.ln1g + (size_t)l * D, *ln1b = P.ln1b + (size_t)l * D;
        const float* Wff1 = P.Wff1 + (size_t)l * D * 2 * D, *bff1 = P.bff1 + (size_t)l * 2 * D;
        const float* Wff2 = P.Wff2 + (size_t)l * 2 * D * D, *bff2 = P.bff2 + (size_t)l * D;
        const float* ln2g = P.ln2g + (size_t)l * D, *ln2b = P.ln2b + (size_t)l * D;

        // ---- P4: qkv for 4 tokens/block; wave = token, lane = out channel.
        //      l==0: x = BN(h) computed inline and materialized. ----
        {
            float* xs = sm;  // [4][64]
            int token = cb * 4 + w;
            int b = token >> 8, n = token & (N - 1);
            size_t xi = (size_t)token * D + lane;
            float xv;
            if (l == 0) {
                float hv = P.h[xi];
                xv = P.bn_g[lane] * (hv - P.mean[lane]) * P.inv[lane] + P.bn_b[lane];
                P.x[xi] = xv;
            } else {
                xv = P.x[xi];
            }
            xs[w * D + lane] = xv;
            __syncthreads();
            int head = lane >> 4, dh = lane & (DH - 1);
            size_t oidx = (((size_t)(b * NH + head)) * N + n) * DH + dh;
            float aq = bq[lane], ak = bk[lane], av = bv[lane];
#pragma unroll 8
            for (int kk = 0; kk < D; ++kk) {
                float s0 = xs[w * D + kk];
                aq += s0 * Wq[kk * D + lane];
                ak += s0 * Wk[kk * D + lane];
                av += s0 * Wv[kk * D + lane];
            }
            P.q[oidx] = aq; P.k[oidx] = ak; P.v[oidx] = av;
        }
        grid.sync();

        // ---- P5: fused layer tail. b = cb>>6, q0 = (cb&63)*4 ----
        {
            float* attS = sm;        // [4][64]
            float* xs1 = sm + 256;   // [4][64]
            float* f1s = sm + 512;   // [4][128]
            int b = cb >> 6;
            int q0 = (cb & 63) * 4;
            int bh = b * NH + w;  // wave = head

            const float* kb = P.k + (size_t)bh * N * DH;
            const float* vb = P.v + (size_t)bh * N * DH;
            float4 Kr[4][4], Vr[4][4];
#pragma unroll
            for (int j = 0; j < 4; ++j) {
                int key = lane + 64 * j;
#pragma unroll
                for (int c = 0; c < 4; ++c) {
                    Kr[j][c] = *(const float4*)(kb + (size_t)key * DH + 4 * c);
                    Vr[j][c] = *(const float4*)(vb + (size_t)key * DH + 4 * c);
                }
            }
#pragma unroll
            for (int qq = 0; qq < 4; ++qq) {
                const float* qp = P.q + ((size_t)bh * N + q0 + qq) * DH;  // wave-uniform
                float sq[DH];
#pragma unroll
                for (int d = 0; d < DH; ++d) sq[d] = qp[d] * 0.25f;  // 1/sqrt(16)
                float s[4];
#pragma unroll
                for (int j = 0; j < 4; ++j) {
                    float a = 0.f;
#pragma unroll
                    for (int c = 0; c < 4; ++c)
                        a += sq[4*c+0]*Kr[j][c].x + sq[4*c+1]*Kr[j][c].y +
                             sq[4*c+2]*Kr[j][c].z + sq[4*c+3]*Kr[j][c].w;
                    s[j] = a;
                }
                float m = fmaxf(fmaxf(s[0], s[1]), fmaxf(s[2], s[3]));
#pragma unroll
                for (int off = 32; off > 0; off >>= 1) m = fmaxf(m, __shfl_xor(m, off));
                float p[4], lsum = 0.f;
#pragma unroll
                for (int j = 0; j < 4; ++j) { p[j] = __expf(s[j] - m); lsum += p[j]; }
#pragma unroll
                for (int off = 32; off > 0; off >>= 1) lsum += __shfl_xor(lsum, off);
                float o[DH];
#pragma unroll
                for (int d = 0; d < DH; ++d) o[d] = 0.f;
#pragma unroll
                for (int j = 0; j < 4; ++j) {
#pragma unroll
                    for (int c = 0; c < 4; ++c) {
                        o[4*c+0] += p[j] * Vr[j][c].x;
                        o[4*c+1] += p[j] * Vr[j][c].y;
                        o[4*c+2] += p[j] * Vr[j][c].z;
                        o[4*c+3] += p[j] * Vr[j][c].w;
                    }
                }
#pragma unroll
                for (int d = 0; d < DH; ++d) {
#pragma unroll
                    for (int off = 32; off > 0; off >>= 1) o[d] += __shfl_xor(o[d], off);
                }
                if (lane == 0) {
                    float rl = 1.f / lsum;
#pragma unroll
                    for (int d = 0; d < DH; ++d) attS[qq * D + w * DH + d] = o[d] * rl;
                }
            }
            __syncthreads();

            // post phase: wave = token q0+w, lane = channel
            int token = q0 + w;
            int ch = lane;
            size_t xidx = ((size_t)b * N + token) * D + ch;
            float oo = bo[ch];
#pragma unroll 8
            for (int kk = 0; kk < D; ++kk) oo += attS[w * D + kk] * Wo[kk * D + ch];
            float r = P.x[xidx] + oo;
            float s1 = r, sq1 = r * r;
#pragma unroll
            for (int off = 32; off > 0; off >>= 1) {
                s1 += __shfl_xor(s1, off);
                sq1 += __shfl_xor(sq1, off);
            }
            float mean1 = s1 * (1.0f / D);
            float var1 = sq1 * (1.0f / D) - mean1 * mean1;
            float x1 = ln1g[ch] * (r - mean1) * rsqrtf(var1 + EPS) + ln1b[ch];
            xs1[w * D + ch] = x1;
            __syncthreads();

            float a0 = bff1[ch], a1 = bff1[ch + 64];
#pragma unroll 8
            for (int kk = 0; kk < D; ++kk) {
                float xv = xs1[w * D + kk];
                a0 += xv * Wff1[kk * 2 * D + ch];
                a1 += xv * Wff1[kk * 2 * D + ch + 64];
            }
            f1s[w * 2 * D + ch] = fmaxf(a0, 0.f);
            f1s[w * 2 * D + ch + 64] = fmaxf(a1, 0.f);
            __syncthreads();

            float o2 = bff2[ch];
#pragma unroll 8
            for (int kk = 0; kk < 2 * D; ++kk) o2 += f1s[w * 2 * D + kk] * Wff2[kk * D + ch];
            float r2 = x1 + o2;
            float s2 = r2, sq2 = r2 * r2;
#pragma unroll
            for (int off = 32; off > 0; off >>= 1) {
                s2 += __shfl_xor(s2, off);
                sq2 += __shfl_xor(sq2, off);
            }
            float mean2 = s2 * (1.0f / D);
            float var2 = sq2 * (1.0f / D) - mean2 * mean2;
            P.x[xidx] = ln2g[ch] * (r2 - mean2) * rsqrtf(var2 + EPS) + ln2b[ch];
        }
        if (l == 0) grid.sync();
    }
}

extern "C" void kernel_launch(void* const* d_in, const int* in_sizes, int n_in,
                              void* d_out, int out_size, void* d_ws, size_t ws_size,
                              hipStream_t stream) {
    float* ws = (float*)d_ws;
    Params P;
    P.feature = (const float*)d_in[0];
    P.W1   = (const float*)d_in[1];
    P.b1   = (const float*)d_in[2];
    P.mw   = (const float*)d_in[3];
    P.mb   = (const float*)d_in[4];
    P.bn_g = (const float*)d_in[5];
    P.bn_b = (const float*)d_in[6];
    P.Wq   = (const float*)d_in[7];
    P.bq   = (const float*)d_in[8];
    P.Wk   = (const float*)d_in[9];
    P.bk   = (const float*)d_in[10];
    P.Wv   = (const float*)d_in[11];
    P.bv   = (const float*)d_in[12];
    P.Wo   = (const float*)d_in[13];
    P.bo   = (const float*)d_in[14];
    P.ln1g = (const float*)d_in[15];
    P.ln1b = (const float*)d_in[16];
    P.Wff1 = (const float*)d_in[17];
    P.bff1 = (const float*)d_in[18];
    P.Wff2 = (const float*)d_in[19];
    P.bff2 = (const float*)d_in[20];
    P.ln2g = (const float*)d_in[21];
    P.ln2b = (const float*)d_in[22];

    P.rs   = ws;                       // B*N*NH = 4096
    P.h    = P.rs + B * N * NH;        // B*N*D  = 65536
    P.mean = P.h + B * N * D;          // D
    P.inv  = P.mean + D;               // D
    P.q    = P.inv + D;                // B*N*D
    P.k    = P.q + B * N * D;          // B*N*D
    P.v    = P.k + B * N * D;          // B*N*D
    P.x    = (float*)d_out;

    void* args[] = {(void*)&P};
    hipLaunchCooperativeKernel(k_all, dim3(256), dim3(256), args, 0, stream);
}

// Round 5
// 165.402 us; speedup vs baseline: 2.1074x; 2.1074x over previous
//
#include <hip/hip_runtime.h>
#include <math.h>

#define B 4
#define N 256
#define DIN 4
#define D 64
#define NH 4
#define NL 2
#define DH 16

constexpr float EPS = 1e-5f;
constexpr float SLOPE = 0.01f;

// ---------------------------------------------------------------------------
// P1: rowsum. grid 256, block 256. Wave w -> row bi = cb*4+w; lane owns 4 j's.
// Block 0 also zero-inits the BN stat accumulators (consumed two kernels later).
// ---------------------------------------------------------------------------
__global__ void __launch_bounds__(256) k_rowsum(
    const float* __restrict__ feature, const float* __restrict__ W1,
    const float* __restrict__ b1, const float* __restrict__ mw,
    const float* __restrict__ mb, float* __restrict__ rs,
    float* __restrict__ bnacc /* [128]: macc|sacc */) {
    __shared__ float M[16];
    __shared__ float C[4];
    int t = threadIdx.x;
    int lane = t & 63, w = t >> 6;
    int cb = blockIdx.x;
    if (cb == 0 && t < 128) bnacc[t] = 0.f;
    if (t < 16) {
        int n = t >> 2, kk = t & 3;
        float s = 0.f;
        for (int d = 0; d < D; ++d) s += W1[kk * D + d] * mw[n * D + d];
        M[t] = s;
    } else if (t < 20) {
        int n = t - 16;
        float s = mb[n];
        for (int d = 0; d < D; ++d) s += b1[d] * mw[n * D + d];
        C[n] = s;
    }
    __syncthreads();

    int bi = cb * 4 + w;
    const float4* fb = (const float4*)(feature) + (size_t)bi * N;
    float sn[4] = {0.f, 0.f, 0.f, 0.f};
#pragma unroll
    for (int m = 0; m < 4; ++m) {
        float4 f = fb[lane + 64 * m];
#pragma unroll
        for (int n = 0; n < 4; ++n) {
            float s = C[n] + f.x * M[n*4+0] + f.y * M[n*4+1] + f.z * M[n*4+2] + f.w * M[n*4+3];
            s = (s >= 0.f) ? s : SLOPE * s;
            sn[n] += __expf(s);
        }
    }
#pragma unroll
    for (int n = 0; n < 4; ++n)
#pragma unroll
        for (int off = 32; off > 0; off >>= 1) sn[n] += __shfl_xor(sn[n], off);
    if (lane == 0) {
        float4 o = {sn[0], sn[1], sn[2], sn[3]};
        *(float4*)(rs + (size_t)bi * 4) = o;
    }
}

// ---------------------------------------------------------------------------
// P2: aggregate + h projection + BN partial sums (atomic).
// grid 256 (b = cb>>6, j0 = (cb&63)*4), block 256 (thread = i, 64B contiguous).
// ---------------------------------------------------------------------------
__global__ void __launch_bounds__(256) k_aggregate(
    const float* __restrict__ feature, const float* __restrict__ W1,
    const float* __restrict__ b1, const float* __restrict__ mw,
    const float* __restrict__ mb, const float* __restrict__ rs,
    float* __restrict__ h, float* __restrict__ bnacc) {
    __shared__ float M[16];
    __shared__ float C[4];
    __shared__ float part[80];   // [4 waves][20]
    __shared__ float gacc[20];   // [4][5]
    __shared__ float hs[4][D];
    int t = threadIdx.x;
    int lane = t & 63, w = t >> 6;
    int cb = blockIdx.x;
    if (t < 16) {
        int n = t >> 2, kk = t & 3;
        float s = 0.f;
        for (int d = 0; d < D; ++d) s += W1[kk * D + d] * mw[n * D + d];
        M[t] = s;
    } else if (t < 20) {
        int n = t - 16;
        float s = mb[n];
        for (int d = 0; d < D; ++d) s += b1[d] * mw[n * D + d];
        C[n] = s;
    }
    __syncthreads();

    int b = cb >> 6, j0 = (cb & 63) * 4;
    int i = t;
    const float4* fb = (const float4*)(feature) + ((size_t)(b * N + i) * N + j0);
    float4 f[4];
#pragma unroll
    for (int jj = 0; jj < 4; ++jj) f[jj] = fb[jj];
    float4 r4 = *(const float4*)(rs + (size_t)(b * N + i) * 4);
    float rinv[4] = {1.f / r4.x, 1.f / r4.y, 1.f / r4.z, 1.f / r4.w};
    float acc[4][5];
#pragma unroll
    for (int jj = 0; jj < 4; ++jj) {
        float wbar = 0.f;
#pragma unroll
        for (int n = 0; n < 4; ++n) {
            float s = C[n] + f[jj].x * M[n*4+0] + f[jj].y * M[n*4+1] + f[jj].z * M[n*4+2] + f[jj].w * M[n*4+3];
            s = (s >= 0.f) ? s : SLOPE * s;
            wbar += __expf(s) * rinv[n];
        }
        wbar *= 0.25f;
        acc[jj][0] = wbar * f[jj].x; acc[jj][1] = wbar * f[jj].y;
        acc[jj][2] = wbar * f[jj].z; acc[jj][3] = wbar * f[jj].w;
        acc[jj][4] = wbar;
    }
#pragma unroll
    for (int jj = 0; jj < 4; ++jj)
#pragma unroll
        for (int c = 0; c < 5; ++c)
#pragma unroll
            for (int off = 32; off > 0; off >>= 1) acc[jj][c] += __shfl_xor(acc[jj][c], off);
    if (lane == 0) {
#pragma unroll
        for (int jj = 0; jj < 4; ++jj)
#pragma unroll
            for (int c = 0; c < 5; ++c) part[w * 20 + jj * 5 + c] = acc[jj][c];
    }
    __syncthreads();
    if (t < 20) gacc[t] = part[t] + part[20 + t] + part[40 + t] + part[60 + t];
    __syncthreads();
    // h write: wave w = token j0+w, lane = channel
    float hv = gacc[w * 5 + 4] * b1[lane];
#pragma unroll
    for (int kk = 0; kk < 4; ++kk) hv += gacc[w * 5 + kk] * W1[kk * D + lane];
    h[((size_t)(b * N + j0 + w)) * D + lane] = hv;
    hs[w][lane] = hv;
    __syncthreads();
    if (w == 0) {
        float s = hs[0][lane] + hs[1][lane] + hs[2][lane] + hs[3][lane];
        float sq = hs[0][lane]*hs[0][lane] + hs[1][lane]*hs[1][lane]
                 + hs[2][lane]*hs[2][lane] + hs[3][lane]*hs[3][lane];
        atomicAdd(bnacc + lane, s);
        atomicAdd(bnacc + D + lane, sq);
    }
}

// ---------------------------------------------------------------------------
// P3: BN finalize + apply + QKV for layer 0.
// grid 256, block 256: wave = token cb*4+w, lane = channel.
// ---------------------------------------------------------------------------
__global__ void __launch_bounds__(256) k_qkv0(
    const float* __restrict__ h, const float* __restrict__ bnacc,
    const float* __restrict__ bn_g, const float* __restrict__ bn_b,
    const float* __restrict__ Wq, const float* __restrict__ bq,
    const float* __restrict__ Wk, const float* __restrict__ bk,
    const float* __restrict__ Wv, const float* __restrict__ bv,
    float* __restrict__ x, float* __restrict__ q,
    float* __restrict__ k, float* __restrict__ v) {
    __shared__ float xs[4][D];
    int t = threadIdx.x;
    int lane = t & 63, w = t >> 6;
    int token = blockIdx.x * 4 + w;
    int b = token >> 8, n = token & (N - 1);
    float mean = bnacc[lane] * (1.0f / (B * N));
    float var = bnacc[D + lane] * (1.0f / (B * N)) - mean * mean;
    float inv = rsqrtf(var + EPS);
    size_t xi = (size_t)token * D + lane;
    float xv = bn_g[lane] * (h[xi] - mean) * inv + bn_b[lane];
    x[xi] = xv;
    xs[w][lane] = xv;
    __syncthreads();
    int head = lane >> 4, dh = lane & (DH - 1);
    size_t oidx = (((size_t)(b * NH + head)) * N + n) * DH + dh;
    float aq = bq[lane], ak = bk[lane], av = bv[lane];
#pragma unroll 8
    for (int kk = 0; kk < D; ++kk) {
        float s0 = xs[w][kk];
        aq += s0 * Wq[kk * D + lane];
        ak += s0 * Wk[kk * D + lane];
        av += s0 * Wv[kk * D + lane];
    }
    q[oidx] = aq; k[oidx] = ak; v[oidx] = av;
}

// ---------------------------------------------------------------------------
// Fused layer tail: attention + O-proj + LN1 + FFN + LN2, optionally + QKV
// for the NEXT layer (block-local: the post-phase holds each token's full
// updated x-row). grid = (B, N/4), block = 256.
// ---------------------------------------------------------------------------
__global__ void __launch_bounds__(256, 2) k_layer(
    const float* __restrict__ q, const float* __restrict__ k,
    const float* __restrict__ v,
    const float* __restrict__ Wo, const float* __restrict__ bo,
    const float* __restrict__ ln1g, const float* __restrict__ ln1b,
    const float* __restrict__ Wff1, const float* __restrict__ bff1,
    const float* __restrict__ Wff2, const float* __restrict__ bff2,
    const float* __restrict__ ln2g, const float* __restrict__ ln2b,
    const float* __restrict__ Wqn, const float* __restrict__ bqn,
    const float* __restrict__ Wkn, const float* __restrict__ bkn,
    const float* __restrict__ Wvn, const float* __restrict__ bvn,
    float* __restrict__ qo, float* __restrict__ ko, float* __restrict__ vo,
    float* __restrict__ x) {
    __shared__ float attS[4][D];   // also reused as x-new for fused next-QKV
    __shared__ float xs1[4][D];
    __shared__ float f1s[4][2 * D];
    int t = threadIdx.x;
    int lane = t & 63, w = t >> 6;
    int b = blockIdx.x;
    int q0 = blockIdx.y * 4;
    int bh = b * NH + w;  // wave = head in attention phase

    const float* kb = k + (size_t)bh * N * DH;
    const float* vb = v + (size_t)bh * N * DH;
    float4 Kr[4][4], Vr[4][4];
#pragma unroll
    for (int j = 0; j < 4; ++j) {
        int key = lane + 64 * j;
#pragma unroll
        for (int c = 0; c < 4; ++c) {
            Kr[j][c] = *(const float4*)(kb + (size_t)key * DH + 4 * c);
            Vr[j][c] = *(const float4*)(vb + (size_t)key * DH + 4 * c);
        }
    }
#pragma unroll
    for (int qq = 0; qq < 4; ++qq) {
        const float* qp = q + ((size_t)bh * N + q0 + qq) * DH;  // wave-uniform
        float sq[DH];
#pragma unroll
        for (int d = 0; d < DH; ++d) sq[d] = qp[d] * 0.25f;  // 1/sqrt(16)
        float s[4];
#pragma unroll
        for (int j = 0; j < 4; ++j) {
            float a = 0.f;
#pragma unroll
            for (int c = 0; c < 4; ++c)
                a += sq[4*c+0]*Kr[j][c].x + sq[4*c+1]*Kr[j][c].y +
                     sq[4*c+2]*Kr[j][c].z + sq[4*c+3]*Kr[j][c].w;
            s[j] = a;
        }
        float m = fmaxf(fmaxf(s[0], s[1]), fmaxf(s[2], s[3]));
#pragma unroll
        for (int off = 32; off > 0; off >>= 1) m = fmaxf(m, __shfl_xor(m, off));
        float p[4], lsum = 0.f;
#pragma unroll
        for (int j = 0; j < 4; ++j) { p[j] = __expf(s[j] - m); lsum += p[j]; }
#pragma unroll
        for (int off = 32; off > 0; off >>= 1) lsum += __shfl_xor(lsum, off);
        float o[DH];
#pragma unroll
        for (int d = 0; d < DH; ++d) o[d] = 0.f;
#pragma unroll
        for (int j = 0; j < 4; ++j) {
#pragma unroll
            for (int c = 0; c < 4; ++c) {
                o[4*c+0] += p[j] * Vr[j][c].x;
                o[4*c+1] += p[j] * Vr[j][c].y;
                o[4*c+2] += p[j] * Vr[j][c].z;
                o[4*c+3] += p[j] * Vr[j][c].w;
            }
        }
#pragma unroll
        for (int d = 0; d < DH; ++d) {
#pragma unroll
            for (int off = 32; off > 0; off >>= 1) o[d] += __shfl_xor(o[d], off);
        }
        if (lane == 0) {
            float rl = 1.f / lsum;
#pragma unroll
            for (int d = 0; d < DH; ++d) attS[qq][w * DH + d] = o[d] * rl;
        }
    }
    __syncthreads();

    // ----- post phase: wave = token q0+w, lane = channel -----
    int token = q0 + w;
    int ch = lane;
    size_t xidx = ((size_t)b * N + token) * D + ch;
    float oo = bo[ch];
#pragma unroll 8
    for (int kk = 0; kk < D; ++kk) oo += attS[w][kk] * Wo[kk * D + ch];
    float r = x[xidx] + oo;
    float s1 = r, sq1 = r * r;
#pragma unroll
    for (int off = 32; off > 0; off >>= 1) {
        s1 += __shfl_xor(s1, off);
        sq1 += __shfl_xor(sq1, off);
    }
    float mean1 = s1 * (1.0f / D);
    float var1 = sq1 * (1.0f / D) - mean1 * mean1;
    float x1 = ln1g[ch] * (r - mean1) * rsqrtf(var1 + EPS) + ln1b[ch];
    xs1[w][ch] = x1;
    __syncthreads();

    float a0 = bff1[ch], a1 = bff1[ch + 64];
#pragma unroll 8
    for (int kk = 0; kk < D; ++kk) {
        float xv = xs1[w][kk];
        a0 += xv * Wff1[kk * 2 * D + ch];
        a1 += xv * Wff1[kk * 2 * D + ch + 64];
    }
    f1s[w][ch] = fmaxf(a0, 0.f);
    f1s[w][ch + 64] = fmaxf(a1, 0.f);
    __syncthreads();

    float o2 = bff2[ch];
#pragma unroll 8
    for (int kk = 0; kk < 2 * D; ++kk) o2 += f1s[w][kk] * Wff2[kk * D + ch];
    float r2 = x1 + o2;
    float s2 = r2, sq2 = r2 * r2;
#pragma unroll
    for (int off = 32; off > 0; off >>= 1) {
        s2 += __shfl_xor(s2, off);
        sq2 += __shfl_xor(sq2, off);
    }
    float mean2 = s2 * (1.0f / D);
    float var2 = sq2 * (1.0f / D) - mean2 * mean2;
    float xnew = ln2g[ch] * (r2 - mean2) * rsqrtf(var2 + EPS) + ln2b[ch];
    x[xidx] = xnew;

    // ----- fused next-layer QKV (block-local) -----
    if (Wqn != nullptr) {
        __syncthreads();              // all waves past their f1s/attS reads
        attS[w][ch] = xnew;           // reuse attS as x-new tile
        __syncthreads();
        int head = ch >> 4, dh = ch & (DH - 1);
        size_t oidx = (((size_t)(b * NH + head)) * N + token) * DH + dh;
        float aq = bqn[ch], ak = bkn[ch], av = bvn[ch];
#pragma unroll 8
        for (int kk = 0; kk < D; ++kk) {
            float s0 = attS[w][kk];
            aq += s0 * Wqn[kk * D + ch];
            ak += s0 * Wkn[kk * D + ch];
            av += s0 * Wvn[kk * D + ch];
        }
        qo[oidx] = aq; ko[oidx] = ak; vo[oidx] = av;
    }
}

extern "C" void kernel_launch(void* const* d_in, const int* in_sizes, int n_in,
                              void* d_out, int out_size, void* d_ws, size_t ws_size,
                              hipStream_t stream) {
    const float* feature = (const float*)d_in[0];
    const float* W1   = (const float*)d_in[1];
    const float* b1   = (const float*)d_in[2];
    const float* mw   = (const float*)d_in[3];
    const float* mb   = (const float*)d_in[4];
    const float* bn_g = (const float*)d_in[5];
    const float* bn_b = (const float*)d_in[6];
    const float* Wq   = (const float*)d_in[7];
    const float* bq   = (const float*)d_in[8];
    const float* Wk   = (const float*)d_in[9];
    const float* bk   = (const float*)d_in[10];
    const float* Wv   = (const float*)d_in[11];
    const float* bv   = (const float*)d_in[12];
    const float* Wo   = (const float*)d_in[13];
    const float* bo   = (const float*)d_in[14];
    const float* ln1g = (const float*)d_in[15];
    const float* ln1b = (const float*)d_in[16];
    const float* Wff1 = (const float*)d_in[17];
    const float* bff1 = (const float*)d_in[18];
    const float* Wff2 = (const float*)d_in[19];
    const float* bff2 = (const float*)d_in[20];
    const float* ln2g = (const float*)d_in[21];
    const float* ln2b = (const float*)d_in[22];

    float* ws    = (float*)d_ws;
    float* rs    = ws;                     // B*N*NH = 4096
    float* h     = rs + B * N * NH;        // B*N*D  = 65536
    float* bnacc = h + B * N * D;          // 128 (macc|sacc)
    float* q     = bnacc + 128;            // B*N*D
    float* k     = q + B * N * D;          // B*N*D
    float* v     = k + B * N * D;          // B*N*D
    float* x     = (float*)d_out;          // running (B,N,D) activation

    k_rowsum<<<256, 256, 0, stream>>>(feature, W1, b1, mw, mb, rs, bnacc);
    k_aggregate<<<256, 256, 0, stream>>>(feature, W1, b1, mw, mb, rs, h, bnacc);
    k_qkv0<<<256, 256, 0, stream>>>(h, bnacc, bn_g, bn_b,
                                    Wq, bq, Wk, bk, Wv, bv, x, q, k, v);
    // layer 0 (fuses layer-1 QKV), then layer 1
    k_layer<<<dim3(B, N / 4), 256, 0, stream>>>(q, k, v,
        Wo, bo, ln1g, ln1b, Wff1, bff1, Wff2, bff2, ln2g, ln2b,
        Wq + (size_t)D * D, bq + D, Wk + (size_t)D * D, bk + D,
        Wv + (size_t)D * D, bv + D, q, k, v, x);
    k_layer<<<dim3(B, N / 4), 256, 0, stream>>>(q, k, v,
        Wo + (size_t)D * D, bo + D, ln1g + D, ln1b + D,
        Wff1 + (size_t)D * 2 * D, bff1 + 2 * D,
        Wff2 + (size_t)2 * D * D, bff2 + D, ln2g + D, ln2b + D,
        nullptr, nullptr, nullptr, nullptr, nullptr, nullptr,
        nullptr, nullptr, nullptr, x);
}